// Round 10
// baseline (90.998 us; speedup 1.0000x reference)
//
#include <hip/hip_runtime.h>
#include <stdint.h>

constexpr int Dz = 96, Hy = 160, Wx = 160;
constexpr int NVOX = Dz * Hy * Wx;

// Stage-1 footprint of a 32d x 32w x 2h block (x=53d/32, z=19w/32, y=159h/160).
// x-origin aligned down to a 4-dword boundary -> pitch 56 dwords = 14 16B chunks.
constexpr int ZSPAN = 20, YSPAN = 3, XPITCH = 56;  // 56 = 14 chunks of 4 dwords
constexpr int ROWS = ZSPAN * YSPAN;                // 60 (z,y) rows
constexpr int NCHUNK = ROWS * 14;                  // 840 16B chunks per plane
constexpr int U = 4;                               // 4 width-16 load rounds (256 threads x 4 >= 840)
constexpr int LBUF = U * 256 * 4;                  // 4096 dwords (16 KB) per buffer

typedef __attribute__((address_space(3))) float lds_f;
typedef __attribute__((address_space(1))) const void gbl_v;

__global__ __launch_bounds__(256) void st_fused_kernel(
    const float* __restrict__ src,
    const float* __restrict__ flows,
    const float* __restrict__ rfp,
    float* __restrict__ out)
{
    __shared__ float raw[2][LBUF];   // 32 KB double buffer; reused for output transpose
    const int t = threadIdx.x;

    // XCD-aware bijective swizzle: 1200 blocks = 8 XCDs x 150
    const int bid = blockIdx.x;
    const int swz = (bid & 7) * 150 + (bid >> 3);
    const int bx = swz % 5;
    const int rest = swz / 5;
    const int by = rest % 3;
    const int bz = rest / 3;
    const int w0 = bx * 32, d0 = by * 32, h0 = bz * 2;
    const float rf = *rfp;

    const int Z0 = (19 * w0) >> 5;
    const int X0 = (53 * d0) >> 5;       // integral (d0 % 32 == 0)
    const int X0a = X0 & ~3;             // 16B-aligned x-origin
    const int YB = (159 * h0) / 160;

    // ---- 4 live 64-bit chunk addresses (16B each), incremented by plane stride ----
    const char* ap[U];
    {
        const char* fb = (const char*)flows + ((size_t)(Z0 * Hy + YB) * Wx + X0a) * 4;
#pragma unroll
        for (int u = 0; u < U; ++u) {
            int c = t + u * 256;
            if (c >= NCHUNK) c = NCHUNK - 1;   // junk dup chunks (never read)
            int row = c / 14;
            int ch  = c - row * 14;
            int z = row / YSPAN;
            int y = row - z * YSPAN;
            ap[u] = fb + ((z * Hy + y) * Wx) * 4 + ch * 16;
        }
    }

    const int wv = t >> 6;   // wave id 0..3
    auto issue_loads = [&](float* lb) {
#pragma unroll
        for (int u = 0; u < U; ++u) {
            __builtin_amdgcn_global_load_lds(
                (gbl_v*)ap[u],
                (lds_f*)&lb[wv * 256 + u * 1024],   // wave-uniform base; HW adds lane*16
                16, 0, 0);
        }
#pragma unroll
        for (int u = 0; u < U; ++u) ap[u] += (size_t)NVOX * 4;
    };

    // ---- compute-phase mapping: lanes vary d (stage-2 x axis = stride 1) ----
    const int dl = t & 31;                      // lane: d
    const int wg = t >> 5;                      // thread-group: w base
    const int d  = d0 + dl;

    // per-lane x interp (stage-1), relative to aligned origin
    const float xf = (float)(53 * d) * (1.0f / 32.0f);
    const int   x0i = (int)xf;
    const float fx  = xf - (float)x0i;
    const int   xx  = x0i - X0a;                // 0..54
    const float wxa = 1.0f - fx, wxb = fx;

    // per-k z interp (stage-1): w = w0 + wg + 8k
    int zzk[4]; float wz0[4], wz1[4];
#pragma unroll
    for (int k = 0; k < 4; ++k) {
        const int w = w0 + wg + 8 * k;
        const float zf = (float)(19 * w) * (1.0f / 32.0f);
        const int z0i = (int)zf;
        const float fz = zf - (float)z0i;
        zzk[k] = z0i - Z0;                      // 0..18
        wz0[k] = 1.0f - fz; wz1[k] = fz;
    }

    float wyr[2][3];
#pragma unroll
    for (int j = 0; j < 2; ++j) {
        const int h = h0 + j;
        const float yf = (float)h * (159.0f / 160.0f);
        const int y0i = (int)yf;
        const float fy = yf - (float)y0i;
        const int yrel = y0i - YB;              // 0 or 1
        const float a = 1.0f - fy, b = fy;
        wyr[j][0] = (yrel == 0) ? a : 0.0f;
        wyr[j][1] = (yrel == 0) ? b : a;
        wyr[j][2] = (yrel == 0) ? 0.0f : b;
    }

    auto compute = [&](const float* lb, float (&v)[4][2]) {
#pragma unroll
        for (int k = 0; k < 4; ++k) {
            const float* base = lb + zzk[k] * (YSPAN * XPITCH) + xx;
            float zv[3];
#pragma unroll
            for (int yy = 0; yy < 3; ++yy) {
                const float* r0 = base + yy * XPITCH;
                const float a0 = r0[0], a1 = r0[1];                              // z0 row
                const float b0 = r0[YSPAN * XPITCH], b1 = r0[YSPAN * XPITCH + 1]; // z1 row
                const float xv0 = wxa * a0 + wxb * a1;
                const float xv1 = wxa * b0 + wxb * b1;
                zv[yy] = wz0[k] * xv0 + wz1[k] * xv1;
            }
#pragma unroll
            for (int j = 0; j < 2; ++j)
                v[k][j] = wyr[j][0] * zv[0] + wyr[j][1] * zv[1] + wyr[j][2] * zv[2];
        }
    };

    float accA[4][2], accB[4][2], accC[4][2];
#pragma unroll
    for (int k = 0; k < 4; ++k)
#pragma unroll
        for (int j = 0; j < 2; ++j) { accA[k][j] = 0.f; accB[k][j] = 0.f; accC[k][j] = 0.f; }

    // ---- double-buffered plane pipeline (round-7 skeleton): 1 barrier/plane ----
    issue_loads(&raw[0][0]);   // plane 0
#pragma unroll
    for (int p = 0; p < 9; ++p) {
        __syncthreads();                        // vmcnt drain publishes plane p; frees other buffer
        if (p < 8) issue_loads(&raw[(p + 1) & 1][0]);
        float v[4][2];
        compute(&raw[p & 1][0], v);
        const int c = p % 3;                    // static (p unrolled)
        if (c == 0) {
#pragma unroll
            for (int k = 0; k < 4; ++k) { accA[k][0] += v[k][0]; accA[k][1] += v[k][1]; }
        } else if (c == 1) {
#pragma unroll
            for (int k = 0; k < 4; ++k) { accB[k][0] += v[k][0]; accB[k][1] += v[k][1]; }
        } else {
#pragma unroll
            for (int k = 0; k < 4; ++k) { accC[k][0] += v[k][0]; accC[k][1] += v[k][1]; }
        }
    }

    // ---- stage 2: sample src (zeros mode); per-lane d -> x-axis coalesced gathers ----
    float res[4][2];
#pragma unroll
    for (int j = 0; j < 2; ++j) {
        const int h = h0 + j;
#pragma unroll
        for (int k = 0; k < 4; ++k) {
            const int w = w0 + wg + 8 * k;
            const float f0 = (float)d + accA[k][j] * rf;   // -> x axis of src
            const float f1 = (float)h + accB[k][j] * rf;   // -> y axis
            const float f2 = (float)w + accC[k][j] * rf;   // -> z axis

            const float xs = f0 * (159.0f / 95.0f);
            const float ys = f1;
            const float zs = f2 * (95.0f / 159.0f);

            const float xs0f = floorf(xs), ys0f = floorf(ys), zs0f = floorf(zs);
            const float gx = xs - xs0f, gy = ys - ys0f, gz = zs - zs0f;
            const int xi0 = (int)xs0f, yi0 = (int)ys0f, zi0 = (int)zs0f;
            const int xi1 = xi0 + 1, yi1 = yi0 + 1, zi1 = zi0 + 1;

            auto samp = [&](int zi, int yi, int xi, float wt) -> float {
                bool valid = ((unsigned)zi < (unsigned)Dz)
                           & ((unsigned)yi < (unsigned)Hy)
                           & ((unsigned)xi < (unsigned)Wx);
                int zc = min(max(zi, 0), Dz - 1);
                int yc = min(max(yi, 0), Hy - 1);
                int xc = min(max(xi, 0), Wx - 1);
                float v = src[(zc * Hy + yc) * Wx + xc];
                return valid ? wt * v : 0.0f;
            };

            res[k][j] = samp(zi0, yi0, xi0, (1.0f - gz) * (1.0f - gy) * (1.0f - gx))
                      + samp(zi0, yi0, xi1, (1.0f - gz) * (1.0f - gy) * gx)
                      + samp(zi0, yi1, xi0, (1.0f - gz) * gy * (1.0f - gx))
                      + samp(zi0, yi1, xi1, (1.0f - gz) * gy * gx)
                      + samp(zi1, yi0, xi0, gz * (1.0f - gy) * (1.0f - gx))
                      + samp(zi1, yi0, xi1, gz * (1.0f - gy) * gx)
                      + samp(zi1, yi1, xi0, gz * gy * (1.0f - gx))
                      + samp(zi1, yi1, xi1, gz * gy * gx);
        }
    }

    // ---- output transpose in LDS (reuse raw; rows padded +1 -> conflict-free) ----
    __syncthreads();                            // all waves done reading plane buffers
    float* tr = &raw[0][0];                     // [2][32][33] floats = 8448 B
#pragma unroll
    for (int j = 0; j < 2; ++j)
#pragma unroll
        for (int k = 0; k < 4; ++k)
            tr[(j * 32 + dl) * 33 + (wg + 8 * k)] = res[k][j];
    __syncthreads();

    const int wl = t & 31;
    const int rg = t >> 5;
#pragma unroll
    for (int j = 0; j < 2; ++j)
#pragma unroll
        for (int m = 0; m < 4; ++m) {
            const int dr = rg + 8 * m;
            out[((size_t)(d0 + dr) * Hy + (h0 + j)) * Wx + (w0 + wl)] =
                tr[(j * 32 + dr) * 33 + wl];
        }
}

extern "C" void kernel_launch(void* const* d_in, const int* in_sizes, int n_in,
                              void* d_out, int out_size, void* d_ws, size_t ws_size,
                              hipStream_t stream) {
    const float* src   = (const float*)d_in[0];
    const float* flows = (const float*)d_in[1];
    const float* rfp   = (const float*)d_in[2];
    float* out = (float*)d_out;

    st_fused_kernel<<<dim3(1200), 256, 0, stream>>>(src, flows, rfp, out);
}

// Round 11
// 42.825 us; speedup vs baseline: 2.1249x; 2.1249x over previous
//
#include <hip/hip_runtime.h>
#include <stdint.h>

constexpr int Dz = 96, Hy = 160, Wx = 160;
constexpr int NVOX = Dz * Hy * Wx;

// Stage-1 footprint of a 32d x 32w x 2h block (x=53d/32, z=19w/32, y=159h/160)
constexpr int ZSPAN = 20, YSPAN = 3, XSPAN = 53;   // unpadded, i-linear LDS layout
constexpr int NL = ZSPAN * YSPAN * XSPAN;          // 3180 floats per plane
constexpr int NSLOT = (NL + 255) / 256;            // 13 load slots per thread (= vmcnt ticks/wave/plane)
constexpr int LBUF = NSLOT * 256;                  // 3328 floats per buffer (tail junk ok)

typedef __attribute__((address_space(3))) float lds_f;
typedef __attribute__((address_space(1))) const void gbl_v;

// Counted-vmcnt barrier: retire the oldest loads only; keep deeper prefetch in flight.
#define PLANE_SYNC(N)                                          \
    asm volatile("s_waitcnt vmcnt(" #N ")" ::: "memory");      \
    __builtin_amdgcn_s_barrier();                              \
    __builtin_amdgcn_sched_barrier(0)

__global__ __launch_bounds__(256) void st_fused_kernel(
    const float* __restrict__ src,
    const float* __restrict__ flows,
    const float* __restrict__ rfp,
    float* __restrict__ out)
{
    __shared__ float raw[3][LBUF];   // 39936 B triple buffer (depth-2 prefetch) -> 4 blocks/CU
    const int t = threadIdx.x;

    // XCD-aware bijective swizzle: 1200 blocks = 8 XCDs x 150
    const int bid = blockIdx.x;
    const int swz = (bid & 7) * 150 + (bid >> 3);
    const int bx = swz % 5;
    const int rest = swz / 5;
    const int by = rest % 3;
    const int bz = rest / 3;
    const int w0 = bx * 32, d0 = by * 32, h0 = bz * 2;
    const float rf = *rfp;

    const int Z0 = (19 * w0) >> 5;
    const int X0 = (53 * d0) >> 5;
    const int YB = (159 * h0) / 160;

    // ---- 13 live 64-bit load addresses, incremented by plane stride ----
    const char* ap[NSLOT];
    {
        const char* fb = (const char*)flows + ((size_t)(Z0 * Hy + YB) * Wx + X0) * 4;
#pragma unroll
        for (int u = 0; u < NSLOT; ++u) {
            int i = t + u * 256;
            int ic = i < NL ? i : NL - 1;      // tail lanes: clamped dup loads (LDS junk, never read)
            int r = ic / XSPAN;
            int x = ic - r * XSPAN;
            int z = r / YSPAN;
            int y = r - z * YSPAN;
            ap[u] = fb + ((z * Hy + y) * Wx + x) * 4;
        }
    }

    auto issue_loads = [&](float* lb) {
#pragma unroll
        for (int u = 0; u < NSLOT; ++u) {
            __builtin_amdgcn_global_load_lds(
                (gbl_v*)ap[u], (lds_f*)&lb[t + u * 256], 4, 0, 0);
        }
#pragma unroll
        for (int u = 0; u < NSLOT; ++u) ap[u] += (size_t)NVOX * 4;
    };

    // ---- compute-phase mapping: lanes vary d (stage-2 x axis = stride 1) ----
    const int dl = t & 31;                      // lane: d
    const int wg = t >> 5;                      // thread-group: w base
    const int d  = d0 + dl;

    // per-lane x interp (stage-1)
    const float xf = (float)(53 * d) * (1.0f / 32.0f);
    const int   x0i = (int)xf;
    const float fx  = xf - (float)x0i;
    const int   xx  = x0i - X0;                 // 0..51
    const float wxa = 1.0f - fx, wxb = fx;

    // per-k z interp (stage-1): w = w0 + wg + 8k
    int zzk[4]; float wz0[4], wz1[4];
#pragma unroll
    for (int k = 0; k < 4; ++k) {
        const int w = w0 + wg + 8 * k;
        const float zf = (float)(19 * w) * (1.0f / 32.0f);
        const int z0i = (int)zf;
        const float fz = zf - (float)z0i;
        zzk[k] = z0i - Z0;                      // 0..18
        wz0[k] = 1.0f - fz; wz1[k] = fz;
    }

    float wyr[2][3];
#pragma unroll
    for (int j = 0; j < 2; ++j) {
        const int h = h0 + j;
        const float yf = (float)h * (159.0f / 160.0f);
        const int y0i = (int)yf;
        const float fy = yf - (float)y0i;
        const int yrel = y0i - YB;              // 0 or 1
        const float a = 1.0f - fy, b = fy;
        wyr[j][0] = (yrel == 0) ? a : 0.0f;
        wyr[j][1] = (yrel == 0) ? b : a;
        wyr[j][2] = (yrel == 0) ? 0.0f : b;
    }

    auto compute = [&](const float* lb, float (&v)[4][2]) {
#pragma unroll
        for (int k = 0; k < 4; ++k) {
            const float* base = lb + zzk[k] * (YSPAN * XSPAN) + xx;
            float zv[3];
#pragma unroll
            for (int yy = 0; yy < 3; ++yy) {
                const float* r0 = base + yy * XSPAN;
                const float a0 = r0[0], a1 = r0[1];                          // z0 row
                const float b0 = r0[YSPAN * XSPAN], b1 = r0[YSPAN * XSPAN + 1]; // z1 row
                const float xv0 = wxa * a0 + wxb * a1;
                const float xv1 = wxa * b0 + wxb * b1;
                zv[yy] = wz0[k] * xv0 + wz1[k] * xv1;
            }
#pragma unroll
            for (int j = 0; j < 2; ++j)
                v[k][j] = wyr[j][0] * zv[0] + wyr[j][1] * zv[1] + wyr[j][2] * zv[2];
        }
    };

    float accA[4][2], accB[4][2], accC[4][2];
#pragma unroll
    for (int k = 0; k < 4; ++k)
#pragma unroll
        for (int j = 0; j < 2; ++j) { accA[k][j] = 0.f; accB[k][j] = 0.f; accC[k][j] = 0.f; }

#define ACC_ADD(ACC) do { float v[4][2]; compute(q0, v); \
    _Pragma("unroll") \
    for (int k = 0; k < 4; ++k) { ACC[k][0] += v[k][0]; ACC[k][1] += v[k][1]; } } while (0)
#define ROT3() do { float* tmp = q0; q0 = q1; q1 = q2; q2 = tmp; } while (0)

    // ---- triple-buffer pipeline: depth-2 prefetch, counted vmcnt, 1 raw barrier/plane.
    // At plane p's barrier: p landed (wait 13 leaves p+1 in flight); p+2's target buffer
    // was computed at p-1, and the barrier proves all waves finished it.
    issue_loads(&raw[0][0]);   // plane 0
    issue_loads(&raw[1][0]);   // plane 1
    float* q0 = &raw[0][0];
    float* q1 = &raw[1][0];
    float* q2 = &raw[2][0];

#pragma unroll 1
    for (int i = 0; i < 2; ++i) {           // planes 0..5
        PLANE_SYNC(13);                     // plane 3i+0 landed; 1 plane stays in flight
        issue_loads(q2);                    // plane 3i+2
        ACC_ADD(accA);
        ROT3();

        PLANE_SYNC(13);                     // plane 3i+1
        issue_loads(q2);                    // plane 3i+3
        ACC_ADD(accB);
        ROT3();

        PLANE_SYNC(13);                     // plane 3i+2
        issue_loads(q2);                    // plane 3i+4
        ACC_ADD(accC);
        ROT3();
    }
    PLANE_SYNC(13);                         // plane 6
    issue_loads(q2);                        // plane 8
    ACC_ADD(accA);
    ROT3();
    PLANE_SYNC(13);                         // plane 7
    ACC_ADD(accB);
    ROT3();
    PLANE_SYNC(0);                          // plane 8
    ACC_ADD(accC);

#undef ACC_ADD
#undef ROT3

    // ---- stage 2: sample src (zeros mode); per-lane d -> x-axis coalesced gathers ----
    float res[4][2];
#pragma unroll
    for (int j = 0; j < 2; ++j) {
        const int h = h0 + j;
#pragma unroll
        for (int k = 0; k < 4; ++k) {
            const int w = w0 + wg + 8 * k;
            const float f0 = (float)d + accA[k][j] * rf;   // -> x axis of src
            const float f1 = (float)h + accB[k][j] * rf;   // -> y axis
            const float f2 = (float)w + accC[k][j] * rf;   // -> z axis

            const float xs = f0 * (159.0f / 95.0f);
            const float ys = f1;
            const float zs = f2 * (95.0f / 159.0f);

            const float xs0f = floorf(xs), ys0f = floorf(ys), zs0f = floorf(zs);
            const float gx = xs - xs0f, gy = ys - ys0f, gz = zs - zs0f;
            const int xi0 = (int)xs0f, yi0 = (int)ys0f, zi0 = (int)zs0f;
            const int xi1 = xi0 + 1, yi1 = yi0 + 1, zi1 = zi0 + 1;

            auto samp = [&](int zi, int yi, int xi, float wt) -> float {
                bool valid = ((unsigned)zi < (unsigned)Dz)
                           & ((unsigned)yi < (unsigned)Hy)
                           & ((unsigned)xi < (unsigned)Wx);
                int zc = min(max(zi, 0), Dz - 1);
                int yc = min(max(yi, 0), Hy - 1);
                int xc = min(max(xi, 0), Wx - 1);
                float v = src[(zc * Hy + yc) * Wx + xc];
                return valid ? wt * v : 0.0f;
            };

            res[k][j] = samp(zi0, yi0, xi0, (1.0f - gz) * (1.0f - gy) * (1.0f - gx))
                      + samp(zi0, yi0, xi1, (1.0f - gz) * (1.0f - gy) * gx)
                      + samp(zi0, yi1, xi0, (1.0f - gz) * gy * (1.0f - gx))
                      + samp(zi0, yi1, xi1, (1.0f - gz) * gy * gx)
                      + samp(zi1, yi0, xi0, gz * (1.0f - gy) * (1.0f - gx))
                      + samp(zi1, yi0, xi1, gz * (1.0f - gy) * gx)
                      + samp(zi1, yi1, xi0, gz * gy * (1.0f - gx))
                      + samp(zi1, yi1, xi1, gz * gy * gx);
        }
    }

    // ---- output transpose in LDS (reuse raw; rows padded +1 -> conflict-free) ----
    __syncthreads();                            // all waves done reading plane buffers
    float* tr = &raw[0][0];                     // [2][32][33] floats = 8448 B
#pragma unroll
    for (int j = 0; j < 2; ++j)
#pragma unroll
        for (int k = 0; k < 4; ++k)
            tr[(j * 32 + dl) * 33 + (wg + 8 * k)] = res[k][j];
    __syncthreads();

    const int wl = t & 31;
    const int rg = t >> 5;
#pragma unroll
    for (int j = 0; j < 2; ++j)
#pragma unroll
        for (int m = 0; m < 4; ++m) {
            const int dr = rg + 8 * m;
            out[((size_t)(d0 + dr) * Hy + (h0 + j)) * Wx + (w0 + wl)] =
                tr[(j * 32 + dr) * 33 + wl];
        }
}

extern "C" void kernel_launch(void* const* d_in, const int* in_sizes, int n_in,
                              void* d_out, int out_size, void* d_ws, size_t ws_size,
                              hipStream_t stream) {
    const float* src   = (const float*)d_in[0];
    const float* flows = (const float*)d_in[1];
    const float* rfp   = (const float*)d_in[2];
    float* out = (float*)d_out;

    st_fused_kernel<<<dim3(1200), 256, 0, stream>>>(src, flows, rfp, out);
}

// Round 12
// 39.926 us; speedup vs baseline: 2.2792x; 1.0726x over previous
//
#include <hip/hip_runtime.h>
#include <stdint.h>

constexpr int Dz = 96, Hy = 160, Wx = 160;
constexpr int NVOX = Dz * Hy * Wx;

// Wave-autonomous tile: 32d x 8w x 2h per WAVE; 4 independent waves per block.
// Stage-1 footprint per wave: 6 z-rows x 3 y-rows x 56-dword aligned x-pitch.
// Proven bounds: zz<=4 (zz+1<=5), Z0w+5<=95, YB+2<=159, X0a+55<=159.
constexpr int ZW = 6, YW = 3, XP = 56;          // LDS plane: [6][3][56] dwords
constexpr int ROWS = ZW * YW;                   // 18 (z,y) rows
constexpr int NCHUNK = ROWS * 14;               // 252 16B chunks per plane
constexpr int UI = 4;                           // width-16 issues/lane/plane (4*64=256>=252)
constexpr int WBUF = UI * 64 * 4;               // 1024 dwords per wave buffer

typedef __attribute__((address_space(3))) float lds_f;
typedef __attribute__((address_space(1))) const void gbl_v;

// Per-wave counted waits (vmcnt is a per-wave counter -> no barriers needed).
#define WAIT_VM(N)  do { asm volatile("s_waitcnt vmcnt(" #N ")" ::: "memory"); \
                         __builtin_amdgcn_sched_barrier(0); } while (0)
#define WAIT_LGKM() do { asm volatile("s_waitcnt lgkmcnt(0)" ::: "memory"); \
                         __builtin_amdgcn_sched_barrier(0); } while (0)

__global__ __launch_bounds__(256) void st_fused_kernel(
    const float* __restrict__ src,
    const float* __restrict__ flows,
    const float* __restrict__ rfp,
    float* __restrict__ out)
{
    __shared__ float raw[4][2][WBUF];   // 32768 B: per-wave private double buffers
    const int t = threadIdx.x;
    const int v = t >> 6;               // wave id 0..3
    const int lane = t & 63;

    // XCD-aware bijective swizzle (1200 = 8 x 150), then wave-linear tiling
    const int bid = blockIdx.x;
    const int swz = (bid & 7) * 150 + (bid >> 3);
    const int wid = swz * 4 + v;        // 0..4799
    const int wt = wid % 20;            // w-tile (8 w each)
    const int rest = wid / 20;
    const int dt = rest % 3;            // d-tile (32 d each)
    const int hp = rest / 3;            // h-pair 0..79
    const int w0w = wt * 8, d0 = dt * 32, h0 = hp * 2;
    const float rf = *rfp;

    const int Z0w = (19 * w0w) >> 5;
    const int X0 = 53 * dt;             // (53*d0)/32 exact
    const int X0a = X0 & ~3;            // 16B-aligned x origin
    const int YB = (159 * h0) / 160;

    // ---- 4 live chunk addresses (16B each), advanced by plane stride ----
    const char* ap[UI];
    {
        const char* fb = (const char*)flows + ((size_t)YB * Wx + X0a) * 4;
#pragma unroll
        for (int u = 0; u < UI; ++u) {
            int c = u * 64 + lane;
            if (c >= NCHUNK) c = NCHUNK - 1;     // tail dups (LDS junk, never read)
            int row = c / 14, ch = c - row * 14;
            int zr = row / 3, yr = row - zr * 3;
            ap[u] = fb + ((size_t)((Z0w + zr) * Hy + yr) * Wx) * 4 + ch * 16;
        }
    }

    auto issue_loads = [&](int buf) {
        lds_f* lb = (lds_f*)&raw[v][buf][0];     // wave-uniform base; HW adds lane*16B
#pragma unroll
        for (int u = 0; u < UI; ++u)
            __builtin_amdgcn_global_load_lds((gbl_v*)ap[u], lb + u * 256, 16, 0, 0);
#pragma unroll
        for (int u = 0; u < UI; ++u) ap[u] += (size_t)NVOX * 4;
    };

    // ---- compute mapping: lanes vary d (stage-2 x axis = stride 1) ----
    const int dl = lane & 31;
    const int half = lane >> 5;         // picks w quartet
    const int d = d0 + dl;

    const float xf = (float)(53 * d) * (1.0f / 32.0f);
    const int   x0i = (int)xf;
    const float fx  = xf - (float)x0i;
    const int   xx  = x0i - X0a;        // 0..54
    const float wxa = 1.0f - fx, wxb = fx;

    int zzk[4]; float wz0k[4], wz1k[4];
#pragma unroll
    for (int k = 0; k < 4; ++k) {
        const int w = w0w + 4 * half + k;
        const float zf = (float)(19 * w) * (1.0f / 32.0f);
        const int z0i = (int)zf;
        const float fz = zf - (float)z0i;
        zzk[k] = z0i - Z0w;             // 0..4
        wz0k[k] = 1.0f - fz; wz1k[k] = fz;
    }

    float wyr[2][3];
#pragma unroll
    for (int j = 0; j < 2; ++j) {
        const int h = h0 + j;
        const float yf = (float)h * (159.0f / 160.0f);
        const int y0i = (int)yf;
        const float fy = yf - (float)y0i;
        const int yrel = y0i - YB;      // 0 or 1
        const float a = 1.0f - fy, b = fy;
        wyr[j][0] = (yrel == 0) ? a : 0.0f;
        wyr[j][1] = (yrel == 0) ? b : a;
        wyr[j][2] = (yrel == 0) ? 0.0f : b;
    }

    auto compute = [&](const float* lb, float (&vv)[4][2]) {
#pragma unroll
        for (int k = 0; k < 4; ++k) {
            const float* base = lb + zzk[k] * (YW * XP) + xx;
            float zv[3];
#pragma unroll
            for (int yy = 0; yy < 3; ++yy) {
                const float* r0 = base + yy * XP;
                const float a0 = r0[0], a1 = r0[1];                  // row zz
                const float b0 = r0[YW * XP], b1 = r0[YW * XP + 1];  // row zz+1
                const float xv0 = wxa * a0 + wxb * a1;
                const float xv1 = wxa * b0 + wxb * b1;
                zv[yy] = wz0k[k] * xv0 + wz1k[k] * xv1;
            }
#pragma unroll
            for (int j = 0; j < 2; ++j)
                vv[k][j] = wyr[j][0] * zv[0] + wyr[j][1] * zv[1] + wyr[j][2] * zv[2];
        }
    };

    float accA[4][2], accB[4][2], accC[4][2];
#pragma unroll
    for (int k = 0; k < 4; ++k)
#pragma unroll
        for (int j = 0; j < 2; ++j) { accA[k][j] = 0.f; accB[k][j] = 0.f; accC[k][j] = 0.f; }

#define ACC_ADD(ACC) do { float vv[4][2]; compute(&raw[v][cur][0], vv); \
    _Pragma("unroll") \
    for (int k = 0; k < 4; ++k) { ACC[k][0] += vv[k][0]; ACC[k][1] += vv[k][1]; } } while (0)

    // ---- barrier-free per-wave pipeline: dbuf, counted vmcnt ----
    issue_loads(0);      // plane 0
    issue_loads(1);      // plane 1
    int cur = 0;

#pragma unroll 1
    for (int i = 0; i < 2; ++i) {       // planes 0..5
        WAIT_VM(4);                     // plane 3i+0 landed; next plane stays in flight
        ACC_ADD(accA);
        issue_loads(cur); cur ^= 1;     // plane 3i+2

        WAIT_VM(4);                     // plane 3i+1
        ACC_ADD(accB);
        issue_loads(cur); cur ^= 1;     // plane 3i+3

        WAIT_VM(4);                     // plane 3i+2
        ACC_ADD(accC);
        issue_loads(cur); cur ^= 1;     // plane 3i+4
    }
    WAIT_VM(4);                         // plane 6
    ACC_ADD(accA);
    issue_loads(cur); cur ^= 1;         // plane 8
    WAIT_VM(4);                         // plane 7
    ACC_ADD(accB);
    cur ^= 1;
    WAIT_VM(0);                         // plane 8
    ACC_ADD(accC);
#undef ACC_ADD

    // ---- stage 2: sample src (zeros mode); per-lane d -> x-axis coalesced gathers ----
    float res[4][2];
#pragma unroll
    for (int j = 0; j < 2; ++j) {
        const int h = h0 + j;
#pragma unroll
        for (int k = 0; k < 4; ++k) {
            const int w = w0w + 4 * half + k;
            const float f0 = (float)d + accA[k][j] * rf;   // -> x axis of src
            const float f1 = (float)h + accB[k][j] * rf;   // -> y axis
            const float f2 = (float)w + accC[k][j] * rf;   // -> z axis

            const float xs = f0 * (159.0f / 95.0f);
            const float ys = f1;
            const float zs = f2 * (95.0f / 159.0f);

            const float xs0f = floorf(xs), ys0f = floorf(ys), zs0f = floorf(zs);
            const float gx = xs - xs0f, gy = ys - ys0f, gz = zs - zs0f;
            const int xi0 = (int)xs0f, yi0 = (int)ys0f, zi0 = (int)zs0f;
            const int xi1 = xi0 + 1, yi1 = yi0 + 1, zi1 = zi0 + 1;

            auto samp = [&](int zi, int yi, int xi, float wt) -> float {
                bool valid = ((unsigned)zi < (unsigned)Dz)
                           & ((unsigned)yi < (unsigned)Hy)
                           & ((unsigned)xi < (unsigned)Wx);
                int zc = min(max(zi, 0), Dz - 1);
                int yc = min(max(yi, 0), Hy - 1);
                int xc = min(max(xi, 0), Wx - 1);
                float vs = src[(zc * Hy + yc) * Wx + xc];
                return valid ? wt * vs : 0.0f;
            };

            res[k][j] = samp(zi0, yi0, xi0, (1.0f - gz) * (1.0f - gy) * (1.0f - gx))
                      + samp(zi0, yi0, xi1, (1.0f - gz) * (1.0f - gy) * gx)
                      + samp(zi0, yi1, xi0, (1.0f - gz) * gy * (1.0f - gx))
                      + samp(zi0, yi1, xi1, (1.0f - gz) * gy * gx)
                      + samp(zi1, yi0, xi0, gz * (1.0f - gy) * (1.0f - gx))
                      + samp(zi1, yi0, xi1, gz * (1.0f - gy) * gx)
                      + samp(zi1, yi1, xi0, gz * gy * (1.0f - gx))
                      + samp(zi1, yi1, xi1, gz * gy * gx);
        }
    }

    // ---- wave-private output transpose (no barriers; lgkmcnt-ordered) ----
    // All staging retired (vmcnt(0) at plane 8); res data-depends on every LDS read.
    float* tr = &raw[v][0][0];          // 2 tiles of [32][9] dwords (576 <= 1024)
#pragma unroll
    for (int j = 0; j < 2; ++j)
#pragma unroll
        for (int k = 0; k < 4; ++k)
            tr[j * 288 + dl * 9 + 4 * half + k] = res[k][j];
    WAIT_LGKM();

    const int rrow = lane >> 3;         // 0..7
    const int rcol = lane & 7;          // 0..7
#pragma unroll
    for (int j = 0; j < 2; ++j)
#pragma unroll
        for (int m = 0; m < 4; ++m) {
            const int dr = m * 8 + rrow;
            out[((size_t)(d0 + dr) * Hy + (h0 + j)) * Wx + (w0w + rcol)] =
                tr[j * 288 + dr * 9 + rcol];
        }
}

extern "C" void kernel_launch(void* const* d_in, const int* in_sizes, int n_in,
                              void* d_out, int out_size, void* d_ws, size_t ws_size,
                              hipStream_t stream) {
    const float* src   = (const float*)d_in[0];
    const float* flows = (const float*)d_in[1];
    const float* rfp   = (const float*)d_in[2];
    float* out = (float*)d_out;

    st_fused_kernel<<<dim3(1200), 256, 0, stream>>>(src, flows, rfp, out);
}

// Round 13
// 30.539 us; speedup vs baseline: 2.9797x; 1.3074x over previous
//
#include <hip/hip_runtime.h>
#include <stdint.h>

constexpr int Dz = 96, Hy = 160, Wx = 160;
constexpr int NVOX = Dz * Hy * Wx;

// Wave-autonomous tile: 32d x 8w x 2h per WAVE; 2 waves per 128-thread block.
// Stage-1 footprint per wave: 6 z-rows x 3 y-rows x 56-dword aligned x-pitch.
constexpr int ZW = 6, YW = 3, XP = 56;          // LDS plane: [6][3][56] dwords
constexpr int ROWS = ZW * YW;                   // 18 (z,y) rows
constexpr int NCHUNK = ROWS * 14;               // 252 16B chunks per plane
constexpr int UI = 4;                           // width-16 issues/lane/plane
constexpr int WBUF = UI * 64 * 4;               // 1024 dwords per wave buffer

typedef __attribute__((address_space(3))) float lds_f;
typedef __attribute__((address_space(1))) const void gbl_v;

#define WAIT_VM(N)  do { asm volatile("s_waitcnt vmcnt(" #N ")" ::: "memory"); \
                         __builtin_amdgcn_sched_barrier(0); } while (0)
#define WAIT_LGKM() do { asm volatile("s_waitcnt lgkmcnt(0)" ::: "memory"); \
                         __builtin_amdgcn_sched_barrier(0); } while (0)

__global__ __launch_bounds__(128) void st_fused_kernel(
    const float* __restrict__ src,
    const float* __restrict__ flows,
    const float* __restrict__ rfp,
    float* __restrict__ out)
{
    __shared__ float raw[2][2][WBUF];   // 16384 B: per-wave private double buffers
    const int t = threadIdx.x;
    const int v = t >> 6;               // wave id 0..1
    const int lane = t & 63;

    // XCD-aware bijective swizzle (2400 = 8 x 300), then wave-linear tiling
    const int bid = blockIdx.x;
    const int swz = (bid & 7) * 300 + (bid >> 3);
    const int wid = swz * 2 + v;        // 0..4799
    const int wt = wid % 20;            // w-tile (8 w each)
    const int rest = wid / 20;
    const int dt = rest % 3;            // d-tile (32 d each)
    const int hp = rest / 3;            // h-pair 0..79
    const int w0w = wt * 8, d0 = dt * 32, h0 = hp * 2;
    const float rf = *rfp;

    const int Z0w = (19 * w0w) >> 5;
    const int X0 = 53 * dt;             // (53*d0)/32 exact
    const int X0a = X0 & ~3;            // 16B-aligned x origin
    const int YB = (159 * h0) / 160;

    // ---- 4 live chunk addresses (16B each), advanced by plane stride ----
    const char* ap[UI];
    {
        const char* fb = (const char*)flows + ((size_t)YB * Wx + X0a) * 4;
#pragma unroll
        for (int u = 0; u < UI; ++u) {
            int c = u * 64 + lane;
            if (c >= NCHUNK) c = NCHUNK - 1;     // tail dups (LDS junk, never read)
            int row = c / 14, ch = c - row * 14;
            int zr = row / 3, yr = row - zr * 3;
            ap[u] = fb + ((size_t)((Z0w + zr) * Hy + yr) * Wx) * 4 + ch * 16;
        }
    }

    auto issue_loads = [&](int buf) {
        lds_f* lb = (lds_f*)&raw[v][buf][0];     // wave-uniform base; HW adds lane*16B
#pragma unroll
        for (int u = 0; u < UI; ++u)
            __builtin_amdgcn_global_load_lds((gbl_v*)ap[u], lb + u * 256, 16, 0, 0);
#pragma unroll
        for (int u = 0; u < UI; ++u) ap[u] += (size_t)NVOX * 4;
    };

    // ---- compute mapping: lanes vary d (stage-2 x axis = stride 1) ----
    const int dl = lane & 31;
    const int half = lane >> 5;         // picks w quartet
    const int d = d0 + dl;

    const float xf = (float)(53 * d) * (1.0f / 32.0f);
    const int   x0i = (int)xf;
    const float fx  = xf - (float)x0i;
    const int   xx  = x0i - X0a;        // 0..54
    const float wxa = 1.0f - fx, wxb = fx;

    int zzk[4]; float wz0k[4], wz1k[4];
#pragma unroll
    for (int k = 0; k < 4; ++k) {
        const int w = w0w + 4 * half + k;
        const float zf = (float)(19 * w) * (1.0f / 32.0f);
        const int z0i = (int)zf;
        const float fz = zf - (float)z0i;
        zzk[k] = z0i - Z0w;             // 0..4
        wz0k[k] = 1.0f - fz; wz1k[k] = fz;
    }

    float wyr[2][3];
#pragma unroll
    for (int j = 0; j < 2; ++j) {
        const int h = h0 + j;
        const float yf = (float)h * (159.0f / 160.0f);
        const int y0i = (int)yf;
        const float fy = yf - (float)y0i;
        const int yrel = y0i - YB;      // 0 or 1
        const float a = 1.0f - fy, b = fy;
        wyr[j][0] = (yrel == 0) ? a : 0.0f;
        wyr[j][1] = (yrel == 0) ? b : a;
        wyr[j][2] = (yrel == 0) ? 0.0f : b;
    }

    auto compute = [&](const float* lb, float (&vv)[4][2]) {
#pragma unroll
        for (int k = 0; k < 4; ++k) {
            const float* base = lb + zzk[k] * (YW * XP) + xx;
            float zv[3];
#pragma unroll
            for (int yy = 0; yy < 3; ++yy) {
                const float* r0 = base + yy * XP;
                const float a0 = r0[0], a1 = r0[1];                  // row zz
                const float b0 = r0[YW * XP], b1 = r0[YW * XP + 1];  // row zz+1
                const float xv0 = wxa * a0 + wxb * a1;
                const float xv1 = wxa * b0 + wxb * b1;
                zv[yy] = wz0k[k] * xv0 + wz1k[k] * xv1;
            }
#pragma unroll
            for (int j = 0; j < 2; ++j)
                vv[k][j] = wyr[j][0] * zv[0] + wyr[j][1] * zv[1] + wyr[j][2] * zv[2];
        }
    };

    float accA[4][2], accB[4][2], accC[4][2];
#pragma unroll
    for (int k = 0; k < 4; ++k)
#pragma unroll
        for (int j = 0; j < 2; ++j) { accA[k][j] = 0.f; accB[k][j] = 0.f; accC[k][j] = 0.f; }

#define ACC_ADD(ACC) do { float vv[4][2]; compute(&raw[v][cur][0], vv); \
    _Pragma("unroll") \
    for (int k = 0; k < 4; ++k) { ACC[k][0] += vv[k][0]; ACC[k][1] += vv[k][1]; } } while (0)

    // ---- barrier-free per-wave pipeline: dbuf, counted vmcnt ----
    issue_loads(0);      // plane 0
    issue_loads(1);      // plane 1
    int cur = 0;

#pragma unroll 1
    for (int i = 0; i < 2; ++i) {       // planes 0..5
        WAIT_VM(4);
        ACC_ADD(accA);
        issue_loads(cur); cur ^= 1;

        WAIT_VM(4);
        ACC_ADD(accB);
        issue_loads(cur); cur ^= 1;

        WAIT_VM(4);
        ACC_ADD(accC);
        issue_loads(cur); cur ^= 1;
    }
    WAIT_VM(4);                         // plane 6
    ACC_ADD(accA);
    issue_loads(cur); cur ^= 1;         // plane 8
    WAIT_VM(4);                         // plane 7
    ACC_ADD(accB);
    cur ^= 1;
    WAIT_VM(0);                         // plane 8
    ACC_ADD(accC);
#undef ACC_ADD

    // ---- stage 2: row-paired src sampling (zeros mode); lanes vary d -> x stride-1 ----
    float res[4][2];
#pragma unroll
    for (int j = 0; j < 2; ++j) {
        const int h = h0 + j;
#pragma unroll
        for (int k = 0; k < 4; ++k) {
            const int w = w0w + 4 * half + k;
            const float f0 = (float)d + accA[k][j] * rf;   // -> x axis of src
            const float f1 = (float)h + accB[k][j] * rf;   // -> y axis
            const float f2 = (float)w + accC[k][j] * rf;   // -> z axis

            const float xs = f0 * (159.0f / 95.0f);
            const float ys = f1;
            const float zs = f2 * (95.0f / 159.0f);

            const float xf0 = floorf(xs), yf0 = floorf(ys), zf0 = floorf(zs);
            const float gx = xs - xf0, gy = ys - yf0, gz = zs - zf0;
            const int xi0 = (int)xf0, yi0 = (int)yf0, zi0 = (int)zf0;

            // x pair: one clamped base, select handles borders exactly
            const int xc = min(max(xi0, 0), Wx - 2);
            const bool sx0 = (xi0 == xc);
            const float wx0m = ((unsigned)xi0 < (unsigned)Wx) ? (1.0f - gx) : 0.0f;
            const float wx1m = ((unsigned)(xi0 + 1) < (unsigned)Wx) ? gx : 0.0f;

            const int yc0 = min(max(yi0, 0), Hy - 1);
            const int yc1 = min(max(yi0 + 1, 0), Hy - 1);
            const int zc0 = min(max(zi0, 0), Dz - 1);
            const int zc1 = min(max(zi0 + 1, 0), Dz - 1);
            const float wy0m = ((unsigned)yi0 < (unsigned)Hy) ? (1.0f - gy) : 0.0f;
            const float wy1m = ((unsigned)(yi0 + 1) < (unsigned)Hy) ? gy : 0.0f;
            const float wz0m = ((unsigned)zi0 < (unsigned)Dz) ? (1.0f - gz) : 0.0f;
            const float wz1m = ((unsigned)(zi0 + 1) < (unsigned)Dz) ? gz : 0.0f;

            const float w00 = wz0m * wy0m, w01 = wz0m * wy1m;
            const float w10 = wz1m * wy0m, w11 = wz1m * wy1m;

            float r = 0.0f;
            auto rowadd = [&](int zc, int yc, float wt) {
                const float* p = src + ((size_t)zc * Hy + yc) * Wx + xc;
                const float va = p[0], vb = p[1];
                const float s0 = sx0 ? va : vb;   // value at xi0 (xi0==159 -> vb)
                const float s1 = sx0 ? vb : va;   // value at xi1 (xi0==-1 -> va)
                r += wt * (wx0m * s0 + wx1m * s1);
            };
            rowadd(zc0, yc0, w00);
            rowadd(zc0, yc1, w01);
            rowadd(zc1, yc0, w10);
            rowadd(zc1, yc1, w11);
            res[k][j] = r;
        }
    }

    // ---- wave-private output transpose (no barriers; lgkmcnt-ordered) ----
    float* tr = &raw[v][0][0];          // 2 tiles of [32][9] dwords (576 <= 2048)
#pragma unroll
    for (int j = 0; j < 2; ++j)
#pragma unroll
        for (int k = 0; k < 4; ++k)
            tr[j * 288 + dl * 9 + 4 * half + k] = res[k][j];
    WAIT_LGKM();

    const int rrow = lane >> 3;         // 0..7
    const int rcol = lane & 7;          // 0..7
#pragma unroll
    for (int j = 0; j < 2; ++j)
#pragma unroll
        for (int m = 0; m < 4; ++m) {
            const int dr = m * 8 + rrow;
            out[((size_t)(d0 + dr) * Hy + (h0 + j)) * Wx + (w0w + rcol)] =
                tr[j * 288 + dr * 9 + rcol];
        }
}

extern "C" void kernel_launch(void* const* d_in, const int* in_sizes, int n_in,
                              void* d_out, int out_size, void* d_ws, size_t ws_size,
                              hipStream_t stream) {
    const float* src   = (const float*)d_in[0];
    const float* flows = (const float*)d_in[1];
    const float* rfp   = (const float*)d_in[2];
    float* out = (float*)d_out;

    st_fused_kernel<<<dim3(2400), 128, 0, stream>>>(src, flows, rfp, out);
}